// Round 1
// baseline (778.782 us; speedup 1.0000x reference)
//
#include <hip/hip_runtime.h>

// Problem constants
#define BB 2
#define LL 2048
#define DIM 2048
#define NH 16
#define NKV 4
#define HD 128
#define NREP 4

using bf16x8 = __attribute__((ext_vector_type(8))) short;
using f32x4  = __attribute__((ext_vector_type(4))) float;

__device__ __forceinline__ unsigned short f32_to_bf16(float f) {
  unsigned u = __float_as_uint(f);
  u += 0x7FFFu + ((u >> 16) & 1u);   // RNE
  return (unsigned short)(u >> 16);
}

// ---------------- elementwise casts ----------------
__global__ void cast_bf16_kernel(const float* __restrict__ src,
                                 unsigned short* __restrict__ dst) {
  int i = blockIdx.x * blockDim.x + threadIdx.x;
  float4 v = reinterpret_cast<const float4*>(src)[i];
  ushort4 o;
  o.x = f32_to_bf16(v.x); o.y = f32_to_bf16(v.y);
  o.z = f32_to_bf16(v.z); o.w = f32_to_bf16(v.w);
  reinterpret_cast<ushort4*>(dst)[i] = o;
}

// ---------------- GEMM: C[M,N] = A[M,K] * W[N,K]^T (bf16 in, f32 out) ----------------
// 128x128 tile, BK=32, 256 threads = 4 waves (2x2), each wave 64x64 via 4x4 MFMA frags.
__global__ __launch_bounds__(256) void gemm_bt_kernel(
    const unsigned short* __restrict__ A, const unsigned short* __restrict__ Bw,
    float* __restrict__ C, int M, int N, int K) {
  __shared__ unsigned short As[128 * 40];  // pad 32->40 to break bank conflicts
  __shared__ unsigned short Bs[128 * 40];
  const int tid = threadIdx.x;
  const int bn = blockIdx.x, bm = blockIdx.y;
  const int w = tid >> 6, lane = tid & 63;
  const int wr = w >> 1, wc = w & 1;
  const int lr = lane & 15, lg = lane >> 4;
  const int r0 = tid >> 2, c0 = (tid & 3) << 3;   // staging row / col-group
  const unsigned short* Ap = A + (size_t)(bm * 128) * K;
  const unsigned short* Bp = Bw + (size_t)(bn * 128) * K;
  f32x4 acc[4][4] = {};
  for (int k0 = 0; k0 < K; k0 += 32) {
    uint4 a0 = *reinterpret_cast<const uint4*>(Ap + (size_t)r0 * K + k0 + c0);
    uint4 a1 = *reinterpret_cast<const uint4*>(Ap + (size_t)(r0 + 64) * K + k0 + c0);
    uint4 b0 = *reinterpret_cast<const uint4*>(Bp + (size_t)r0 * K + k0 + c0);
    uint4 b1 = *reinterpret_cast<const uint4*>(Bp + (size_t)(r0 + 64) * K + k0 + c0);
    __syncthreads();
    *reinterpret_cast<uint4*>(As + r0 * 40 + c0) = a0;
    *reinterpret_cast<uint4*>(As + (r0 + 64) * 40 + c0) = a1;
    *reinterpret_cast<uint4*>(Bs + r0 * 40 + c0) = b0;
    *reinterpret_cast<uint4*>(Bs + (r0 + 64) * 40 + c0) = b1;
    __syncthreads();
    bf16x8 af[4], bfr[4];
#pragma unroll
    for (int i = 0; i < 4; ++i)
      af[i] = *reinterpret_cast<const bf16x8*>(As + (wr * 64 + i * 16 + lr) * 40 + lg * 8);
#pragma unroll
    for (int j = 0; j < 4; ++j)
      bfr[j] = *reinterpret_cast<const bf16x8*>(Bs + (wc * 64 + j * 16 + lr) * 40 + lg * 8);
#pragma unroll
    for (int i = 0; i < 4; ++i)
#pragma unroll
      for (int j = 0; j < 4; ++j)
        acc[i][j] = __builtin_amdgcn_mfma_f32_16x16x32_bf16(af[i], bfr[j], acc[i][j], 0, 0, 0);
  }
#pragma unroll
  for (int i = 0; i < 4; ++i) {
    const int m = bm * 128 + wr * 64 + i * 16 + lg * 4;
#pragma unroll
    for (int j = 0; j < 4; ++j) {
      const int n = bn * 128 + wc * 64 + j * 16 + lr;
#pragma unroll
      for (int r = 0; r < 4; ++r)
        C[(size_t)(m + r) * N + n] = acc[i][j][r];
    }
  }
}

// ---------------- RoPE on Q: xq f32 (B,L,H,HD) -> q bf16 same layout ----------------
__global__ void rope_q_kernel(const float* __restrict__ xq, const float* __restrict__ fc,
                              const float* __restrict__ fs, unsigned short* __restrict__ qbf) {
  int idx = blockIdx.x * 256 + threadIdx.x;   // pair index over (b,l,h,i)
  int i = idx & 63;
  int l = (idx >> 10) & 2047;
  float2 t = reinterpret_cast<const float2*>(xq)[idx];
  float c = fc[l * 64 + i], s = fs[l * 64 + i];
  float r0 = t.x * c - t.y * s;
  float r1 = t.x * s + t.y * c;
  ushort2 o; o.x = f32_to_bf16(r0); o.y = f32_to_bf16(r1);
  reinterpret_cast<ushort2*>(qbf)[idx] = o;
}

// ---------------- RoPE on K + write keys output ----------------
// xk f32 (B,L,KV,HD) -> kbf bf16 (B,KV,L,HD), keys f32 (B,NH,L,HD) (repeat 4x)
__global__ void rope_k_kernel(const float* __restrict__ xk, const float* __restrict__ fc,
                              const float* __restrict__ fs, unsigned short* __restrict__ kbf,
                              float* __restrict__ keys) {
  int idx = blockIdx.x * 256 + threadIdx.x;   // pair index over (b,l,kv,i)
  int i = idx & 63;
  int kv = (idx >> 6) & 3;
  int l = (idx >> 8) & 2047;
  int b = idx >> 19;
  float2 t = reinterpret_cast<const float2*>(xk)[idx];
  float c = fc[l * 64 + i], s = fs[l * 64 + i];
  float r0 = t.x * c - t.y * s;
  float r1 = t.x * s + t.y * c;
  int kidx = ((b * 4 + kv) * 2048 + l) * 64 + i;
  ushort2 o; o.x = f32_to_bf16(r0); o.y = f32_to_bf16(r1);
  reinterpret_cast<ushort2*>(kbf)[kidx] = o;
  float2 f; f.x = r0; f.y = r1;
#pragma unroll
  for (int rep = 0; rep < 4; ++rep) {
    int h = kv * 4 + rep;
    reinterpret_cast<float2*>(keys)[((b * 16 + h) * 2048 + l) * 64 + i] = f;
  }
}

// ---------------- V pass: write values output + transposed bf16 V ----------------
// xv f32 (B,L,KV,HD) -> values f32 (B,NH,L,HD), vt bf16 (B,KV,HD,L)
__global__ void v_proc_kernel(const float* __restrict__ xv, unsigned short* __restrict__ vt,
                              float* __restrict__ values) {
  int idx = blockIdx.x * 256 + threadIdx.x;   // element over (b,l,kv,d)
  int d = idx & 127;
  int kv = (idx >> 7) & 3;
  int l = (idx >> 9) & 2047;
  int b = idx >> 20;
  float v = xv[idx];
#pragma unroll
  for (int rep = 0; rep < 4; ++rep) {
    int h = kv * 4 + rep;
    values[((size_t)(b * 16 + h) * 2048 + l) * 128 + d] = v;
  }
  vt[((size_t)(b * 4 + kv) * 128 + d) * 2048 + l] = f32_to_bf16(v);
}

// ---------------- causal flash attention ----------------
// Per wave: 16 q-rows; KV in blocks of 32. q bf16 (B,L,H,HD), k bf16 (B,KV,L,HD),
// vt bf16 (B,KV,HD,L), out bf16 (B,L,DIM).
__global__ __launch_bounds__(256) void attn_kernel(
    const unsigned short* __restrict__ qbf, const unsigned short* __restrict__ kbf,
    const unsigned short* __restrict__ vt, unsigned short* __restrict__ obf) {
  __shared__ unsigned short Pbuf[4][16 * 40];
  const int tid = threadIdx.x;
  const int w = tid >> 6, lane = tid & 63;
  const int lr = lane & 15, lg = lane >> 4;
  const int bh = blockIdx.y;
  const int b = bh >> 4, h = bh & 15, kv = h >> 2;
  const int qbase = blockIdx.x * 64 + w * 16;
  const float SCALE = 0.08838834764831845f;   // 1/sqrt(128)

  bf16x8 qf[4];
  {
    const unsigned short* qp = qbf + ((size_t)((b * 2048 + qbase + lr) * 16 + h)) * 128 + lg * 8;
#pragma unroll
    for (int s = 0; s < 4; ++s) qf[s] = *reinterpret_cast<const bf16x8*>(qp + s * 32);
  }
  f32x4 acc[8] = {};
  float mrow[4], lsum[4];
#pragma unroll
  for (int r = 0; r < 4; ++r) { mrow[r] = -1e30f; lsum[r] = 0.0f; }

  const unsigned short* kbase_p = kbf + (size_t)(b * 4 + kv) * 2048 * 128;
  const unsigned short* vbase_p = vt + (size_t)(b * 4 + kv) * 128 * 2048;

  const int nblocks = (qbase + 47) >> 5;
  for (int j = 0; j < nblocks; ++j) {
    const int kb = j * 32;
    f32x4 s0 = {0.f, 0.f, 0.f, 0.f}, s1 = {0.f, 0.f, 0.f, 0.f};
#pragma unroll
    for (int s = 0; s < 4; ++s) {
      bf16x8 kf = *reinterpret_cast<const bf16x8*>(kbase_p + (size_t)(kb + lr) * 128 + s * 32 + lg * 8);
      s0 = __builtin_amdgcn_mfma_f32_16x16x32_bf16(qf[s], kf, s0, 0, 0, 0);
    }
#pragma unroll
    for (int s = 0; s < 4; ++s) {
      bf16x8 kf = *reinterpret_cast<const bf16x8*>(kbase_p + (size_t)(kb + 16 + lr) * 128 + s * 32 + lg * 8);
      s1 = __builtin_amdgcn_mfma_f32_16x16x32_bf16(qf[s], kf, s1, 0, 0, 0);
    }
    float p0[4], p1[4], fac[4];
#pragma unroll
    for (int r = 0; r < 4; ++r) {
      int q = qbase + lg * 4 + r;
      float v0 = ((kb + lr) <= q) ? s0[r] * SCALE : -1e30f;
      float v1 = ((kb + 16 + lr) <= q) ? s1[r] * SCALE : -1e30f;
      float rm = fmaxf(v0, v1);
      rm = fmaxf(rm, __shfl_xor(rm, 1));
      rm = fmaxf(rm, __shfl_xor(rm, 2));
      rm = fmaxf(rm, __shfl_xor(rm, 4));
      rm = fmaxf(rm, __shfl_xor(rm, 8));
      float mnew = fmaxf(mrow[r], rm);
      p0[r] = __expf(v0 - mnew);
      p1[r] = __expf(v1 - mnew);
      float rs = p0[r] + p1[r];
      rs += __shfl_xor(rs, 1);
      rs += __shfl_xor(rs, 2);
      rs += __shfl_xor(rs, 4);
      rs += __shfl_xor(rs, 8);
      fac[r] = __expf(mrow[r] - mnew);
      lsum[r] = lsum[r] * fac[r] + rs;
      mrow[r] = mnew;
    }
#pragma unroll
    for (int ft = 0; ft < 8; ++ft) {
      acc[ft][0] *= fac[0]; acc[ft][1] *= fac[1];
      acc[ft][2] *= fac[2]; acc[ft][3] *= fac[3];
    }
    // P (D-layout) -> LDS -> A-fragment layout
#pragma unroll
    for (int r = 0; r < 4; ++r) {
      Pbuf[w][(lg * 4 + r) * 40 + lr]      = f32_to_bf16(p0[r]);
      Pbuf[w][(lg * 4 + r) * 40 + 16 + lr] = f32_to_bf16(p1[r]);
    }
    asm volatile("s_waitcnt lgkmcnt(0)" ::: "memory");
    bf16x8 pa = *reinterpret_cast<const bf16x8*>(&Pbuf[w][lr * 40 + lg * 8]);
#pragma unroll
    for (int ft = 0; ft < 8; ++ft) {
      bf16x8 vf = *reinterpret_cast<const bf16x8*>(vbase_p + (size_t)(ft * 16 + lr) * 2048 + kb + lg * 8);
      acc[ft] = __builtin_amdgcn_mfma_f32_16x16x32_bf16(pa, vf, acc[ft], 0, 0, 0);
    }
  }
#pragma unroll
  for (int ft = 0; ft < 8; ++ft) {
#pragma unroll
    for (int r = 0; r < 4; ++r) {
      float o = acc[ft][r] / lsum[r];
      obf[((size_t)(b * 2048 + qbase + lg * 4 + r)) * 2048 + h * 128 + ft * 16 + lr] = f32_to_bf16(o);
    }
  }
}

// ---------------- host launch ----------------
extern "C" void kernel_launch(void* const* d_in, const int* in_sizes, int n_in,
                              void* d_out, int out_size, void* d_ws, size_t ws_size,
                              hipStream_t stream) {
  const float* x  = (const float*)d_in[0];
  const float* fc = (const float*)d_in[1];
  const float* fs = (const float*)d_in[2];
  const float* wq = (const float*)d_in[3];
  const float* wk = (const float*)d_in[4];
  const float* wv = (const float*)d_in[5];
  const float* wo = (const float*)d_in[6];

  float* out    = (float*)d_out;              // (B,L,DIM)
  float* keys   = out + 8388608;              // (B,NH,L,HD)
  float* values = out + 16777216;             // (B,NH,L,HD)

  char* ws = (char*)d_ws;
  unsigned short* WQ  = (unsigned short*)(ws + 0);          //  8 MB
  unsigned short* WK  = (unsigned short*)(ws + 8388608);    //  2 MB
  unsigned short* WV  = (unsigned short*)(ws + 10485760);   //  2 MB
  unsigned short* WO  = (unsigned short*)(ws + 12582912);   //  8 MB
  unsigned short* XBF = (unsigned short*)(ws + 20971520);   // 16 MB (later reused as Q_BF)
  float*          XQF = (float*)(ws + 37748736);            // 32 MB (later reused as ATTN_BF)
  float*          XKF = (float*)(ws + 71303168);            //  8 MB
  float*          XVF = (float*)(ws + 79691776);            //  8 MB
  unsigned short* KBF = (unsigned short*)(ws + 88080384);   //  4 MB
  unsigned short* VTB = (unsigned short*)(ws + 92274688);   //  4 MB
  unsigned short* QBF = XBF;                                // alias (x_bf dead after gemms)
  unsigned short* ATT = (unsigned short*)XQF;               // alias (xq dead after rope_q)

  // casts to bf16
  cast_bf16_kernel<<<4096, 256, 0, stream>>>(wq, WQ);
  cast_bf16_kernel<<<1024, 256, 0, stream>>>(wk, WK);
  cast_bf16_kernel<<<1024, 256, 0, stream>>>(wv, WV);
  cast_bf16_kernel<<<4096, 256, 0, stream>>>(wo, WO);
  cast_bf16_kernel<<<8192, 256, 0, stream>>>(x, XBF);

  // projections
  gemm_bt_kernel<<<dim3(16, 32), 256, 0, stream>>>(XBF, WQ, XQF, 4096, 2048, 2048);
  gemm_bt_kernel<<<dim3(4, 32), 256, 0, stream>>>(XBF, WK, XKF, 4096, 512, 2048);
  gemm_bt_kernel<<<dim3(4, 32), 256, 0, stream>>>(XBF, WV, XVF, 4096, 512, 2048);

  // rope + scatter (QBF aliases XBF: runs after all gemms read XBF)
  rope_q_kernel<<<16384, 256, 0, stream>>>(XQF, fc, fs, QBF);
  rope_k_kernel<<<4096, 256, 0, stream>>>(XKF, fc, fs, KBF, keys);
  v_proc_kernel<<<8192, 256, 0, stream>>>(XVF, VTB, values);

  // attention (ATT aliases XQF region: xq consumed by rope_q)
  attn_kernel<<<dim3(32, 32), 256, 0, stream>>>(QBF, KBF, VTB, ATT);

  // output projection
  gemm_bt_kernel<<<dim3(16, 32), 256, 0, stream>>>(ATT, WO, out, 4096, 2048, 2048);
}

// Round 2
// 357.367 us; speedup vs baseline: 2.1792x; 2.1792x over previous
//
#include <hip/hip_runtime.h>

#define LLEN 2048
#define DIMX 2048

using bf16x8 = __attribute__((ext_vector_type(8))) short;
using f32x4  = __attribute__((ext_vector_type(4))) float;

__device__ __forceinline__ unsigned short f32_to_bf16(float f) {
  unsigned u = __float_as_uint(f);
  u += 0x7FFFu + ((u >> 16) & 1u);   // RNE
  return (unsigned short)(u >> 16);
}
__device__ __forceinline__ unsigned pack_bf16x2(float lo, float hi) {
  return (unsigned)f32_to_bf16(lo) | ((unsigned)f32_to_bf16(hi) << 16);
}
__device__ __forceinline__ void gload_lds16(const void* g, void* l) {
  __builtin_amdgcn_global_load_lds(
      (const __attribute__((address_space(1))) unsigned int*)g,
      (__attribute__((address_space(3))) unsigned int*)l, 16, 0, 0);
}

// ---------------- elementwise casts ----------------
__global__ void cast_bf16_kernel(const float* __restrict__ src,
                                 unsigned short* __restrict__ dst) {
  int i = blockIdx.x * blockDim.x + threadIdx.x;
  float4 v = reinterpret_cast<const float4*>(src)[i];
  ushort4 o;
  o.x = f32_to_bf16(v.x); o.y = f32_to_bf16(v.y);
  o.z = f32_to_bf16(v.z); o.w = f32_to_bf16(v.w);
  reinterpret_cast<ushort4*>(dst)[i] = o;
}

// ---------------- GEMM: C[M,N] = A[M,K] * W[N,K]^T  (m97 structure) ----------------
__global__ __launch_bounds__(256) void gemm_bt_kernel(
    const unsigned short* __restrict__ A, const unsigned short* __restrict__ Bw,
    float* __restrict__ C, int M, int N, int K) {
  __shared__ unsigned short As[128 * 32];   // linear: row-major [128][32], 64B/row
  __shared__ unsigned short Bs[128 * 32];
  const int tid = threadIdx.x;
  const int bn = blockIdx.x, bm = blockIdx.y;
  const int w = tid >> 6, lane = tid & 63;
  const int wr = w >> 1, wc = w & 1;
  const int lr = lane & 15, lg = lane >> 4;
  const int srow = lane >> 2;           // 16 rows per 1KB wave-instr
  const int scolb = (lane & 3) * 16;    // byte col within 64B row
  f32x4 acc[4][4] = {};
  for (int k0 = 0; k0 < K; k0 += 32) {
    __syncthreads();
#pragma unroll
    for (int i = 0; i < 2; ++i) {
      int row = w * 32 + i * 16 + srow;
      gload_lds16((const char*)A + ((size_t)(bm * 128 + row) * K + k0) * 2 + scolb,
                  (char*)As + w * 2048 + i * 1024);
      gload_lds16((const char*)Bw + ((size_t)(bn * 128 + row) * K + k0) * 2 + scolb,
                  (char*)Bs + w * 2048 + i * 1024);
    }
    __syncthreads();
    bf16x8 af[4], bfr[4];
#pragma unroll
    for (int i = 0; i < 4; ++i)
      af[i] = *reinterpret_cast<const bf16x8*>((char*)As + (wr * 64 + i * 16 + lr) * 64 + lg * 16);
#pragma unroll
    for (int j = 0; j < 4; ++j)
      bfr[j] = *reinterpret_cast<const bf16x8*>((char*)Bs + (wc * 64 + j * 16 + lr) * 64 + lg * 16);
#pragma unroll
    for (int i = 0; i < 4; ++i)
#pragma unroll
      for (int j = 0; j < 4; ++j)
        acc[i][j] = __builtin_amdgcn_mfma_f32_16x16x32_bf16(af[i], bfr[j], acc[i][j], 0, 0, 0);
  }
#pragma unroll
  for (int i = 0; i < 4; ++i) {
    const int m = bm * 128 + wr * 64 + i * 16 + lg * 4;
#pragma unroll
    for (int j = 0; j < 4; ++j) {
      const int n = bn * 128 + wc * 64 + j * 16 + lr;
#pragma unroll
      for (int r = 0; r < 4; ++r)
        C[(size_t)(m + r) * N + n] = acc[i][j][r];
    }
  }
}

// ---------------- RoPE on Q ----------------
__global__ void rope_q_kernel(const float* __restrict__ xq, const float* __restrict__ fc,
                              const float* __restrict__ fs, unsigned short* __restrict__ qbf) {
  int idx = blockIdx.x * 256 + threadIdx.x;
  int i = idx & 63;
  int l = (idx >> 10) & 2047;
  float2 t = reinterpret_cast<const float2*>(xq)[idx];
  float c = fc[l * 64 + i], s = fs[l * 64 + i];
  float r0 = t.x * c - t.y * s;
  float r1 = t.x * s + t.y * c;
  ushort2 o; o.x = f32_to_bf16(r0); o.y = f32_to_bf16(r1);
  reinterpret_cast<ushort2*>(qbf)[idx] = o;
}

// ---------------- RoPE on K + keys output ----------------
__global__ void rope_k_kernel(const float* __restrict__ xk, const float* __restrict__ fc,
                              const float* __restrict__ fs, unsigned short* __restrict__ kbf,
                              float* __restrict__ keys) {
  int idx = blockIdx.x * 256 + threadIdx.x;
  int i = idx & 63;
  int kvh = (idx >> 6) & 3;
  int l = (idx >> 8) & 2047;
  int b = idx >> 19;
  float2 t = reinterpret_cast<const float2*>(xk)[idx];
  float c = fc[l * 64 + i], s = fs[l * 64 + i];
  float r0 = t.x * c - t.y * s;
  float r1 = t.x * s + t.y * c;
  int kidx = ((b * 4 + kvh) * 2048 + l) * 64 + i;
  ushort2 o; o.x = f32_to_bf16(r0); o.y = f32_to_bf16(r1);
  reinterpret_cast<ushort2*>(kbf)[kidx] = o;
  float2 f; f.x = r0; f.y = r1;
#pragma unroll
  for (int rep = 0; rep < 4; ++rep) {
    int h = kvh * 4 + rep;
    reinterpret_cast<float2*>(keys)[((b * 16 + h) * 2048 + l) * 64 + i] = f;
  }
}

// ---------------- V pass: values output + transposed bf16 V ----------------
__global__ void v_proc_kernel(const float* __restrict__ xv, unsigned short* __restrict__ vt,
                              float* __restrict__ values) {
  int idx = blockIdx.x * 256 + threadIdx.x;
  int d = idx & 127;
  int kvh = (idx >> 7) & 3;
  int l = (idx >> 9) & 2047;
  int b = idx >> 20;
  float v = xv[idx];
#pragma unroll
  for (int rep = 0; rep < 4; ++rep) {
    int h = kvh * 4 + rep;
    values[((size_t)(b * 16 + h) * 2048 + l) * 128 + d] = v;
  }
  vt[((size_t)(b * 4 + kvh) * 128 + d) * 2048 + l] = f32_to_bf16(v);
}

// ---------------- causal flash attention v2 ----------------
// 4 waves/block, wave owns 32 q-rows (2 x 16-row tiles); KVBLK=64 staged in LDS.
// Swapped QK^T (S^T: k lane-local -> 2-shfl softmax); PV as O^T = V^T * P^T.
__global__ __launch_bounds__(256) void attn_kernel(
    const unsigned short* __restrict__ qbf, const unsigned short* __restrict__ kbf,
    const unsigned short* __restrict__ vt, unsigned short* __restrict__ obf) {
  __shared__ unsigned short Ks[64 * 128];      // [k][d] rows 256B, XOR-swizzled
  __shared__ unsigned short Vs[128 * 64];      // [d][k] rows 128B, XOR-swizzled
  __shared__ unsigned short Ps[4][2][16 * 72]; // per wave, per t: [q16][k64+pad] 144B rows
  const int tid = threadIdx.x;
  const int w = tid >> 6, lane = tid & 63;
  const int lr = lane & 15, lg = lane >> 4;
  const int bid = blockIdx.x;
  const int qt = 15 - (bid >> 5);              // longest tiles dispatched first
  const int bh = bid & 31;
  const int b = bh >> 4, h = bh & 15, kv = h >> 2;
  const int q0 = qt * 128 + w * 32;
  const float SCALE = 0.08838834764831845f;    // 1/sqrt(128)
  const int swz = (lr & 7) << 4;

  // Q fragments (B-operand: lane holds Q[q0+t*16+lr][s*32+lg*8+e])
  bf16x8 qf[2][4];
#pragma unroll
  for (int t = 0; t < 2; ++t) {
    const unsigned short* qp = qbf + ((size_t)((b * 2048 + q0 + t * 16 + lr) * 16 + h)) * 128 + lg * 8;
#pragma unroll
    for (int s = 0; s < 4; ++s) qf[t][s] = *reinterpret_cast<const bf16x8*>(qp + s * 32);
  }
  f32x4 acc[2][8] = {};
  float mrow[2] = {-1e30f, -1e30f}, lsum[2] = {0.f, 0.f};

  const char* kgbase = (const char*)(kbf + (size_t)(b * 4 + kv) * 2048 * 128);
  const char* vgbase = (const char*)(vt + (size_t)(b * 4 + kv) * 128 * 2048);

  const int nblocks = 2 * qt + 2;
  for (int j = 0; j < nblocks; ++j) {
    const int kb = j * 64;
    __syncthreads();
    // stage K[64][128] and V^T[128][64]; linear LDS dest, inverse-swizzled global src
#pragma unroll
    for (int i = 0; i < 4; ++i) {
      int p = w * 4096 + i * 1024 + lane * 16;
      int krow = p >> 8;
      int kcol = (p & 255) ^ ((krow & 7) << 4);
      gload_lds16(kgbase + (size_t)(kb + krow) * 256 + kcol, (char*)Ks + w * 4096 + i * 1024);
      int drow = p >> 7;
      int dcol = (p & 127) ^ ((drow & 7) << 4);
      gload_lds16(vgbase + (size_t)drow * 4096 + (size_t)kb * 2 + dcol, (char*)Vs + w * 4096 + i * 1024);
    }
    __syncthreads();
    // QK^T swapped: sT[t][c] covers S^T[k=c*16+lg*4+r][q=t*16+lr]
    f32x4 sT[2][4];
#pragma unroll
    for (int c = 0; c < 4; ++c) {
      bf16x8 kf[4];
#pragma unroll
      for (int s = 0; s < 4; ++s)
        kf[s] = *reinterpret_cast<const bf16x8*>((char*)Ks + (((c * 16 + lr) * 256 + s * 64 + lg * 16) ^ swz));
      f32x4 t0 = {0.f, 0.f, 0.f, 0.f}, t1 = {0.f, 0.f, 0.f, 0.f};
#pragma unroll
      for (int s = 0; s < 4; ++s) {
        t0 = __builtin_amdgcn_mfma_f32_16x16x32_bf16(kf[s], qf[0][s], t0, 0, 0, 0);
        t1 = __builtin_amdgcn_mfma_f32_16x16x32_bf16(kf[s], qf[1][s], t1, 0, 0, 0);
      }
      sT[0][c] = t0; sT[1][c] = t1;
    }
    // softmax per row-tile; k is lane-local (16 regs) + lg spread (shfl 16,32)
#pragma unroll
    for (int t = 0; t < 2; ++t) {
      const int qrow = q0 + t * 16 + lr;
      float x[4][4];
      float mt = -1e30f;
#pragma unroll
      for (int c = 0; c < 4; ++c)
#pragma unroll
        for (int r = 0; r < 4; ++r) {
          int k = kb + c * 16 + lg * 4 + r;
          float v = (k <= qrow) ? sT[t][c][r] * SCALE : -1e30f;
          x[c][r] = v;
          mt = fmaxf(mt, v);
        }
      mt = fmaxf(mt, __shfl_xor(mt, 16));
      mt = fmaxf(mt, __shfl_xor(mt, 32));
      float mnew = fmaxf(mrow[t], mt);
      float fac = __expf(mrow[t] - mnew);
      mrow[t] = mnew;
      float rs = 0.f;
      unsigned pw[4][2];
#pragma unroll
      for (int c = 0; c < 4; ++c)
#pragma unroll
        for (int j2 = 0; j2 < 2; ++j2) {
          float p0 = __expf(x[c][2 * j2] - mnew);
          float p1 = __expf(x[c][2 * j2 + 1] - mnew);
          rs += p0 + p1;
          pw[c][j2] = pack_bf16x2(p0, p1);
        }
      rs += __shfl_xor(rs, 16);
      rs += __shfl_xor(rs, 32);
      lsum[t] = lsum[t] * fac + rs;
#pragma unroll
      for (int dt = 0; dt < 8; ++dt)
#pragma unroll
        for (int r = 0; r < 4; ++r) acc[t][dt][r] *= fac;
      // transpose P^T -> P[q][k] via per-wave LDS
      char* pb = (char*)&Ps[w][t][0];
#pragma unroll
      for (int c = 0; c < 4; ++c)
#pragma unroll
        for (int j2 = 0; j2 < 2; ++j2)
          *reinterpret_cast<unsigned*>(pb + lr * 144 + c * 32 + lg * 8 + j2 * 4) = pw[c][j2];
    }
    asm volatile("s_waitcnt lgkmcnt(0)" ::: "memory");
    __builtin_amdgcn_sched_barrier(0);
    // PV: O^T += V^T * P^T
    bf16x8 pt[2][2];
#pragma unroll
    for (int t = 0; t < 2; ++t)
#pragma unroll
      for (int kk = 0; kk < 2; ++kk)
        pt[t][kk] = *reinterpret_cast<const bf16x8*>((char*)&Ps[w][t][0] + lr * 144 + kk * 64 + lg * 16);
#pragma unroll
    for (int dt = 0; dt < 8; ++dt) {
      bf16x8 v0 = *reinterpret_cast<const bf16x8*>((char*)Vs + (((dt * 16 + lr) * 128 + lg * 16) ^ swz));
      bf16x8 v1 = *reinterpret_cast<const bf16x8*>((char*)Vs + (((dt * 16 + lr) * 128 + 64 + lg * 16) ^ swz));
      acc[0][dt] = __builtin_amdgcn_mfma_f32_16x16x32_bf16(v0, pt[0][0], acc[0][dt], 0, 0, 0);
      acc[0][dt] = __builtin_amdgcn_mfma_f32_16x16x32_bf16(v1, pt[0][1], acc[0][dt], 0, 0, 0);
      acc[1][dt] = __builtin_amdgcn_mfma_f32_16x16x32_bf16(v0, pt[1][0], acc[1][dt], 0, 0, 0);
      acc[1][dt] = __builtin_amdgcn_mfma_f32_16x16x32_bf16(v1, pt[1][1], acc[1][dt], 0, 0, 0);
    }
  }
  // epilogue: acc[t][dt][r] = O^T[d=dt*16+lg*4+r][q=t*16+lr]
#pragma unroll
  for (int t = 0; t < 2; ++t) {
    float inv = 1.0f / lsum[t];
#pragma unroll
    for (int dt = 0; dt < 8; ++dt) {
      ushort4 o;
      o.x = f32_to_bf16(acc[t][dt][0] * inv);
      o.y = f32_to_bf16(acc[t][dt][1] * inv);
      o.z = f32_to_bf16(acc[t][dt][2] * inv);
      o.w = f32_to_bf16(acc[t][dt][3] * inv);
      *reinterpret_cast<ushort4*>(obf + ((size_t)(b * 2048 + q0 + t * 16 + lr)) * 2048 + h * 128 + dt * 16 + lg * 4) = o;
    }
  }
}

// ---------------- host launch ----------------
extern "C" void kernel_launch(void* const* d_in, const int* in_sizes, int n_in,
                              void* d_out, int out_size, void* d_ws, size_t ws_size,
                              hipStream_t stream) {
  const float* x  = (const float*)d_in[0];
  const float* fc = (const float*)d_in[1];
  const float* fs = (const float*)d_in[2];
  const float* wq = (const float*)d_in[3];
  const float* wk = (const float*)d_in[4];
  const float* wv = (const float*)d_in[5];
  const float* wo = (const float*)d_in[6];

  float* out    = (float*)d_out;
  float* keys   = out + 8388608;
  float* values = out + 16777216;

  char* ws = (char*)d_ws;
  unsigned short* WQ  = (unsigned short*)(ws + 0);
  unsigned short* WK  = (unsigned short*)(ws + 8388608);
  unsigned short* WV  = (unsigned short*)(ws + 10485760);
  unsigned short* WO  = (unsigned short*)(ws + 12582912);
  unsigned short* XBF = (unsigned short*)(ws + 20971520);
  float*          XQF = (float*)(ws + 37748736);
  float*          XKF = (float*)(ws + 71303168);
  float*          XVF = (float*)(ws + 79691776);
  unsigned short* KBF = (unsigned short*)(ws + 88080384);
  unsigned short* VTB = (unsigned short*)(ws + 92274688);
  unsigned short* QBF = XBF;                 // alias (x_bf dead after gemms)
  unsigned short* ATT = (unsigned short*)XQF;// alias (xq dead after rope_q)

  cast_bf16_kernel<<<4096, 256, 0, stream>>>(wq, WQ);
  cast_bf16_kernel<<<1024, 256, 0, stream>>>(wk, WK);
  cast_bf16_kernel<<<1024, 256, 0, stream>>>(wv, WV);
  cast_bf16_kernel<<<4096, 256, 0, stream>>>(wo, WO);
  cast_bf16_kernel<<<8192, 256, 0, stream>>>(x, XBF);

  gemm_bt_kernel<<<dim3(16, 32), 256, 0, stream>>>(XBF, WQ, XQF, 4096, 2048, 2048);
  gemm_bt_kernel<<<dim3(4, 32), 256, 0, stream>>>(XBF, WK, XKF, 4096, 512, 2048);
  gemm_bt_kernel<<<dim3(4, 32), 256, 0, stream>>>(XBF, WV, XVF, 4096, 512, 2048);

  rope_q_kernel<<<16384, 256, 0, stream>>>(XQF, fc, fs, QBF);
  rope_k_kernel<<<4096, 256, 0, stream>>>(XKF, fc, fs, KBF, keys);
  v_proc_kernel<<<8192, 256, 0, stream>>>(XVF, VTB, values);

  attn_kernel<<<512, 256, 0, stream>>>(QBF, KBF, VTB, ATT);

  gemm_bt_kernel<<<dim3(16, 32), 256, 0, stream>>>(ATT, WO, out, 4096, 2048, 2048);
}

// Round 3
// 352.712 us; speedup vs baseline: 2.2080x; 1.0132x over previous
//
#include <hip/hip_runtime.h>
#include <hip/hip_bf16.h>

using bf16x8 = __attribute__((ext_vector_type(8))) short;
using f32x4  = __attribute__((ext_vector_type(4))) float;

__device__ __forceinline__ unsigned short f32_to_bf16(float f) {
  unsigned u = __float_as_uint(f);
  u += 0x7FFFu + ((u >> 16) & 1u);   // RNE
  return (unsigned short)(u >> 16);
}
__device__ __forceinline__ unsigned pack2(float lo, float hi) {
  __hip_bfloat162 h = __float22bfloat162_rn(make_float2(lo, hi)); // v_cvt_pk path
  return *reinterpret_cast<unsigned*>(&h);
}
__device__ __forceinline__ void gload_lds16(const void* g, void* l) {
  __builtin_amdgcn_global_load_lds(
      (const __attribute__((address_space(1))) unsigned int*)g,
      (__attribute__((address_space(3))) unsigned int*)l, 16, 0, 0);
}

// ---------------- elementwise casts ----------------
__global__ void cast_bf16_kernel(const float* __restrict__ src,
                                 unsigned short* __restrict__ dst) {
  int i = blockIdx.x * blockDim.x + threadIdx.x;
  float4 v = reinterpret_cast<const float4*>(src)[i];
  ushort4 o;
  o.x = f32_to_bf16(v.x); o.y = f32_to_bf16(v.y);
  o.z = f32_to_bf16(v.z); o.w = f32_to_bf16(v.w);
  reinterpret_cast<ushort4*>(dst)[i] = o;
}
__global__ void cast2_bf16_kernel(const float* __restrict__ s0, unsigned short* __restrict__ d0,
                                  int n0v, const float* __restrict__ s1,
                                  unsigned short* __restrict__ d1) {
  int i = blockIdx.x * blockDim.x + threadIdx.x;
  const float* s; unsigned short* d; int j;
  if (i < n0v) { s = s0; d = d0; j = i; } else { s = s1; d = d1; j = i - n0v; }
  float4 v = reinterpret_cast<const float4*>(s)[j];
  ushort4 o;
  o.x = f32_to_bf16(v.x); o.y = f32_to_bf16(v.y);
  o.z = f32_to_bf16(v.z); o.w = f32_to_bf16(v.w);
  reinterpret_cast<ushort4*>(d)[j] = o;
}

// ---------------- GEMM: C[M,N] = A[M,K] * W[N,K]^T  (m97 structure) ----------------
__global__ __launch_bounds__(256) void gemm_bt_kernel(
    const unsigned short* __restrict__ A, const unsigned short* __restrict__ Bw,
    float* __restrict__ C, int M, int N, int K) {
  __shared__ unsigned short As[128 * 32];
  __shared__ unsigned short Bs[128 * 32];
  const int tid = threadIdx.x;
  const int bn = blockIdx.x, bm = blockIdx.y;
  const int w = tid >> 6, lane = tid & 63;
  const int wr = w >> 1, wc = w & 1;
  const int lr = lane & 15, lg = lane >> 4;
  const int srow = lane >> 2;
  const int scolb = (lane & 3) * 16;
  f32x4 acc[4][4] = {};
  for (int k0 = 0; k0 < K; k0 += 32) {
    __syncthreads();
#pragma unroll
    for (int i = 0; i < 2; ++i) {
      int row = w * 32 + i * 16 + srow;
      gload_lds16((const char*)A + ((size_t)(bm * 128 + row) * K + k0) * 2 + scolb,
                  (char*)As + w * 2048 + i * 1024);
      gload_lds16((const char*)Bw + ((size_t)(bn * 128 + row) * K + k0) * 2 + scolb,
                  (char*)Bs + w * 2048 + i * 1024);
    }
    __syncthreads();
    bf16x8 af[4], bfr[4];
#pragma unroll
    for (int i = 0; i < 4; ++i)
      af[i] = *reinterpret_cast<const bf16x8*>((char*)As + (wr * 64 + i * 16 + lr) * 64 + lg * 16);
#pragma unroll
    for (int j = 0; j < 4; ++j)
      bfr[j] = *reinterpret_cast<const bf16x8*>((char*)Bs + (wc * 64 + j * 16 + lr) * 64 + lg * 16);
#pragma unroll
    for (int i = 0; i < 4; ++i)
#pragma unroll
      for (int j = 0; j < 4; ++j)
        acc[i][j] = __builtin_amdgcn_mfma_f32_16x16x32_bf16(af[i], bfr[j], acc[i][j], 0, 0, 0);
  }
#pragma unroll
  for (int i = 0; i < 4; ++i) {
    const int m = bm * 128 + wr * 64 + i * 16 + lg * 4;
#pragma unroll
    for (int j = 0; j < 4; ++j) {
      const int n = bn * 128 + wc * 64 + j * 16 + lr;
#pragma unroll
      for (int r = 0; r < 4; ++r)
        C[(size_t)(m + r) * N + n] = acc[i][j][r];
    }
  }
}

// ---------------- RoPE on K + keys output ----------------
__global__ void rope_k_kernel(const float* __restrict__ xk, const float* __restrict__ fc,
                              const float* __restrict__ fs, unsigned short* __restrict__ kbf,
                              float* __restrict__ keys) {
  int idx = blockIdx.x * 256 + threadIdx.x;
  int i = idx & 63;
  int kvh = (idx >> 6) & 3;
  int l = (idx >> 8) & 2047;
  int b = idx >> 19;
  float2 t = reinterpret_cast<const float2*>(xk)[idx];
  float c = fc[l * 64 + i], s = fs[l * 64 + i];
  float r0 = t.x * c - t.y * s;
  float r1 = t.x * s + t.y * c;
  int kidx = ((b * 4 + kvh) * 2048 + l) * 64 + i;
  ushort2 o; o.x = f32_to_bf16(r0); o.y = f32_to_bf16(r1);
  reinterpret_cast<ushort2*>(kbf)[kidx] = o;
  float2 f; f.x = r0; f.y = r1;
#pragma unroll
  for (int rep = 0; rep < 4; ++rep) {
    int h = kvh * 4 + rep;
    reinterpret_cast<float2*>(keys)[((b * 16 + h) * 2048 + l) * 64 + i] = f;
  }
}

// ---------------- V pass: values output + transposed bf16 V ----------------
__global__ void v_proc_kernel(const float* __restrict__ xv, unsigned short* __restrict__ vt,
                              float* __restrict__ values) {
  int idx = blockIdx.x * 256 + threadIdx.x;
  int d = idx & 127;
  int kvh = (idx >> 7) & 3;
  int l = (idx >> 9) & 2047;
  int b = idx >> 20;
  float v = xv[idx];
#pragma unroll
  for (int rep = 0; rep < 4; ++rep) {
    int h = kvh * 4 + rep;
    values[((size_t)(b * 16 + h) * 2048 + l) * 128 + d] = v;
  }
  vt[((size_t)(b * 4 + kvh) * 128 + d) * 2048 + l] = f32_to_bf16(v);
}

// ---------------- causal flash attention v3 ----------------
// K-rows permuted in LDS so PV's B-fragment is a pure in-lane cvt_pk repack
// (no P LDS roundtrip). RoPE-on-Q fused. Diagonal-aligned wave tiling:
// wave w owns rows qt*128+w*16 (t0) and qt*128+64+w*16 (t1).
__global__ __launch_bounds__(256) void attn_kernel(
    const float* __restrict__ xq, const float* __restrict__ fc,
    const float* __restrict__ fs, const unsigned short* __restrict__ kbf,
    const unsigned short* __restrict__ vt, unsigned short* __restrict__ obf) {
  __shared__ unsigned short Ks[64 * 128];   // [slot][d], rows 256B, XOR-swizzled, row-permuted
  __shared__ unsigned short Vs[128 * 64];   // [d][k],  rows 128B, XOR-swizzled
  const int tid = threadIdx.x;
  const int w = tid >> 6, lane = tid & 63;
  const int lr = lane & 15, lg = lane >> 4;
  const int bid = blockIdx.x;
  const int g = bid & 7;                    // XCD slot: one (b,kv) pair per XCD
  const int slot = bid >> 3;
  const int qt = (slot < 32) ? (15 - (slot >> 2)) : ((slot - 32) >> 2);
  const int rep = slot & 3;
  const int b = g >> 2, kv = g & 3;
  const int h = kv * 4 + rep;
  const float SCALE = 0.08838834764831845f; // 1/sqrt(128)
  const int swz = (lr & 7) << 4;

  const int qr0 = qt * 128 + w * 16 + lr;   // t0 row
  const int qr1 = qr0 + 64;                 // t1 row

  // ---- fused RoPE Q-fragment build (B-operand layout) ----
  bf16x8 qf[2][4];
#pragma unroll
  for (int t = 0; t < 2; ++t) {
    const int qrow = t ? qr1 : qr0;
    const float* xqp = xq + ((size_t)(b * 2048 + qrow)) * 2048 + h * 128;
    const float* fcp = fc + qrow * 64;
    const float* fsp = fs + qrow * 64;
#pragma unroll
    for (int s = 0; s < 4; ++s) {
      float4 f0 = *reinterpret_cast<const float4*>(xqp + s * 32 + lg * 8);
      float4 f1 = *reinterpret_cast<const float4*>(xqp + s * 32 + lg * 8 + 4);
      float4 c4 = *reinterpret_cast<const float4*>(fcp + s * 16 + lg * 4);
      float4 s4 = *reinterpret_cast<const float4*>(fsp + s * 16 + lg * 4);
      union { bf16x8 v8; unsigned u[4]; } u;
      u.u[0] = pack2(f0.x * c4.x - f0.y * s4.x, f0.x * s4.x + f0.y * c4.x);
      u.u[1] = pack2(f0.z * c4.y - f0.w * s4.y, f0.z * s4.y + f0.w * c4.y);
      u.u[2] = pack2(f1.x * c4.z - f1.y * s4.z, f1.x * s4.z + f1.y * c4.z);
      u.u[3] = pack2(f1.z * c4.w - f1.w * s4.w, f1.z * s4.w + f1.w * c4.w);
      qf[t][s] = u.v8;
    }
  }

  f32x4 acc[2][8] = {};
  float mrow[2] = {-1e30f, -1e30f}, lsum[2] = {0.f, 0.f};

  const char* kgbase = (const char*)(kbf + (size_t)(b * 4 + kv) * 2048 * 128);
  const char* vgbase = (const char*)(vt + (size_t)(b * 4 + kv) * 128 * 2048);

  // staging source offsets (loop-invariant); K global row permuted by pi
  int ksrc[4], vsrc[4];
#pragma unroll
  for (int i = 0; i < 4; ++i) {
    int p = w * 4096 + i * 1024 + lane * 16;
    int krow = p >> 8;
    int kperm = ((krow >> 5) << 5) + ((krow >> 4) & 1) + (((krow >> 2) & 3) << 3) + ((krow & 3) << 1);
    int kcol = (p & 255) ^ ((krow & 7) << 4);
    ksrc[i] = kperm * 256 + kcol;
    int drow = p >> 7;
    int dcol = (p & 127) ^ ((drow & 7) << 4);
    vsrc[i] = drow * 4096 + dcol;
  }

  // per-t softmax + in-lane P repack
  auto softmax_t = [&](const f32x4* st, int t, bool mask, int qrow, int kb, bf16x8* pt) {
    float xv[4][4];
    float mt = -1e30f;
#pragma unroll
    for (int c = 0; c < 4; ++c)
#pragma unroll
      for (int r = 0; r < 4; ++r) {
        float v = st[c][r] * SCALE;
        if (mask) {
          int ka = kb + ((c >> 1) << 5) + (c & 1) + 8 * lg + 2 * r;
          v = (ka <= qrow) ? v : -1e30f;
        }
        xv[c][r] = v;
        mt = fmaxf(mt, v);
      }
    mt = fmaxf(mt, __shfl_xor(mt, 16));
    mt = fmaxf(mt, __shfl_xor(mt, 32));
    float facm = 1.0f;
    if (!__all(mt <= mrow[t] + 8.0f)) {        // defer-max (T13)
      float mnew = fmaxf(mrow[t], mt);
      facm = __expf(mrow[t] - mnew);
      mrow[t] = mnew;
#pragma unroll
      for (int dt = 0; dt < 8; ++dt)
#pragma unroll
        for (int r = 0; r < 4; ++r) acc[t][dt][r] *= facm;
    }
    float rs = 0.f;
    float pv[4][4];
#pragma unroll
    for (int c = 0; c < 4; ++c)
#pragma unroll
      for (int r = 0; r < 4; ++r) {
        float p = __expf(xv[c][r] - mrow[t]);
        pv[c][r] = p;
        rs += p;
      }
    rs += __shfl_xor(rs, 16);
    rs += __shfl_xor(rs, 32);
    lsum[t] = lsum[t] * facm + rs;
#pragma unroll
    for (int kk = 0; kk < 2; ++kk) {
      union { bf16x8 v8; unsigned u[4]; } u;
#pragma unroll
      for (int wd = 0; wd < 4; ++wd)
        u.u[wd] = pack2(pv[2 * kk][wd], pv[2 * kk + 1][wd]);
      pt[kk] = u.v8;
    }
  };

  auto step = [&](int j, bool do0, bool do1, bool m0, bool m1) {
    const int kb = j * 64;
    __syncthreads();
    const char* kg = kgbase + (size_t)kb * 256;
    const char* vg = vgbase + (size_t)kb * 2;
#pragma unroll
    for (int i = 0; i < 4; ++i) {
      gload_lds16(kg + ksrc[i], (char*)Ks + w * 4096 + i * 1024);
      gload_lds16(vg + vsrc[i], (char*)Vs + w * 4096 + i * 1024);
    }
    __syncthreads();
    // QK^T (swapped): sT[c] = S^T rows (permuted keys), cols = q
    f32x4 sT0[4], sT1[4];
    __builtin_amdgcn_s_setprio(1);
#pragma unroll
    for (int c = 0; c < 4; ++c) {
      bf16x8 kf[4];
#pragma unroll
      for (int s = 0; s < 4; ++s)
        kf[s] = *reinterpret_cast<const bf16x8*>((char*)Ks + (((c * 16 + lr) * 256 + s * 64 + lg * 16) ^ swz));
      f32x4 t0 = {0.f, 0.f, 0.f, 0.f}, t1 = {0.f, 0.f, 0.f, 0.f};
#pragma unroll
      for (int s = 0; s < 4; ++s) {
        if (do0) t0 = __builtin_amdgcn_mfma_f32_16x16x32_bf16(kf[s], qf[0][s], t0, 0, 0, 0);
        if (do1) t1 = __builtin_amdgcn_mfma_f32_16x16x32_bf16(kf[s], qf[1][s], t1, 0, 0, 0);
      }
      sT0[c] = t0; sT1[c] = t1;
    }
    __builtin_amdgcn_s_setprio(0);
    bf16x8 pt0[2], pt1[2];
    if (do0) softmax_t(sT0, 0, m0, qr0, kb, pt0);
    if (do1) softmax_t(sT1, 1, m1, qr1, kb, pt1);
    // PV: O^T += V^T * P^T  (pt is in-lane repack; V unpermuted)
    __builtin_amdgcn_s_setprio(1);
#pragma unroll
    for (int dt = 0; dt < 8; ++dt) {
      bf16x8 v0 = *reinterpret_cast<const bf16x8*>((char*)Vs + (((dt * 16 + lr) * 128 + lg * 16) ^ swz));
      bf16x8 v1 = *reinterpret_cast<const bf16x8*>((char*)Vs + (((dt * 16 + lr) * 128 + 64 + lg * 16) ^ swz));
      if (do0) {
        acc[0][dt] = __builtin_amdgcn_mfma_f32_16x16x32_bf16(v0, pt0[0], acc[0][dt], 0, 0, 0);
        acc[0][dt] = __builtin_amdgcn_mfma_f32_16x16x32_bf16(v1, pt0[1], acc[0][dt], 0, 0, 0);
      }
      if (do1) {
        acc[1][dt] = __builtin_amdgcn_mfma_f32_16x16x32_bf16(v0, pt1[0], acc[1][dt], 0, 0, 0);
        acc[1][dt] = __builtin_amdgcn_mfma_f32_16x16x32_bf16(v1, pt1[1], acc[1][dt], 0, 0, 0);
      }
    }
    __builtin_amdgcn_s_setprio(0);
  };

  const int jd = 2 * qt;
  for (int j = 0; j < jd; ++j) step(j, true, true, false, false);
  step(jd, true, true, true, false);        // t0 diagonal, t1 still full
  step(jd + 1, false, true, false, true);   // t1 diagonal only

#pragma unroll
  for (int t = 0; t < 2; ++t) {
    const int qrow = t ? qr1 : qr0;
    float inv = 1.0f / lsum[t];
#pragma unroll
    for (int dt = 0; dt < 8; ++dt) {
      ushort4 o;
      o.x = f32_to_bf16(acc[t][dt][0] * inv);
      o.y = f32_to_bf16(acc[t][dt][1] * inv);
      o.z = f32_to_bf16(acc[t][dt][2] * inv);
      o.w = f32_to_bf16(acc[t][dt][3] * inv);
      *reinterpret_cast<ushort4*>(obf + ((size_t)(b * 2048 + qrow)) * 2048 + h * 128 + dt * 16 + lg * 4) = o;
    }
  }
}

// ---------------- host launch ----------------
extern "C" void kernel_launch(void* const* d_in, const int* in_sizes, int n_in,
                              void* d_out, int out_size, void* d_ws, size_t ws_size,
                              hipStream_t stream) {
  const float* x  = (const float*)d_in[0];
  const float* fc = (const float*)d_in[1];
  const float* fs = (const float*)d_in[2];
  const float* wq = (const float*)d_in[3];
  const float* wk = (const float*)d_in[4];
  const float* wv = (const float*)d_in[5];
  const float* wo = (const float*)d_in[6];

  float* out    = (float*)d_out;
  float* keys   = out + 8388608;
  float* values = out + 16777216;

  char* ws = (char*)d_ws;
  unsigned short* WQ  = (unsigned short*)(ws + 0);          // 8 MB
  unsigned short* WK  = (unsigned short*)(ws + 8388608);    // 2 MB
  unsigned short* WV  = (unsigned short*)(ws + 10485760);   // 2 MB
  unsigned short* WO  = (unsigned short*)(ws + 12582912);   // 8 MB
  unsigned short* XBF = (unsigned short*)(ws + 20971520);   // 16 MB (reused as ATT)
  float*          XQF = (float*)(ws + 37748736);            // 32 MB (live through attn)
  float*          XKF = (float*)(ws + 71303168);            // 8 MB
  float*          XVF = (float*)(ws + 79691776);            // 8 MB
  unsigned short* KBF = (unsigned short*)(ws + 88080384);   // 4 MB
  unsigned short* VTB = (unsigned short*)(ws + 92274688);   // 4 MB
  unsigned short* ATT = XBF;                                // alias: XBF dead after projections

  cast2_bf16_kernel<<<8192, 256, 0, stream>>>(wq, WQ, 1048576, wo, WO);
  cast2_bf16_kernel<<<2048, 256, 0, stream>>>(wk, WK, 262144, wv, WV);
  cast_bf16_kernel<<<8192, 256, 0, stream>>>(x, XBF);

  gemm_bt_kernel<<<dim3(16, 32), 256, 0, stream>>>(XBF, WQ, XQF, 4096, 2048, 2048);
  gemm_bt_kernel<<<dim3(4, 32), 256, 0, stream>>>(XBF, WK, XKF, 4096, 512, 2048);
  gemm_bt_kernel<<<dim3(4, 32), 256, 0, stream>>>(XBF, WV, XVF, 4096, 512, 2048);

  rope_k_kernel<<<4096, 256, 0, stream>>>(XKF, fc, fs, KBF, keys);
  v_proc_kernel<<<8192, 256, 0, stream>>>(XVF, VTB, values);

  attn_kernel<<<512, 256, 0, stream>>>(XQF, fc, fs, KBF, VTB, ATT);

  gemm_bt_kernel<<<dim3(16, 32), 256, 0, stream>>>(ATT, WO, out, 4096, 2048, 2048);
}

// Round 4
// 287.204 us; speedup vs baseline: 2.7116x; 1.2281x over previous
//
#include <hip/hip_runtime.h>
#include <hip/hip_bf16.h>

using bf16x8 = __attribute__((ext_vector_type(8))) short;
using f32x4  = __attribute__((ext_vector_type(4))) float;

__device__ __forceinline__ unsigned short f32_to_bf16(float f) {
  unsigned u = __float_as_uint(f);
  u += 0x7FFFu + ((u >> 16) & 1u);   // RNE
  return (unsigned short)(u >> 16);
}
__device__ __forceinline__ unsigned pack2(float lo, float hi) {
  __hip_bfloat162 h = __float22bfloat162_rn(make_float2(lo, hi)); // v_cvt_pk path
  return *reinterpret_cast<unsigned*>(&h);
}
__device__ __forceinline__ void gload_lds16(const void* g, void* l) {
  __builtin_amdgcn_global_load_lds(
      (const __attribute__((address_space(1))) unsigned int*)g,
      (__attribute__((address_space(3))) unsigned int*)l, 16, 0, 0);
}

// ---------------- elementwise casts ----------------
__global__ void cast_bf16_kernel(const float* __restrict__ src,
                                 unsigned short* __restrict__ dst) {
  int i = blockIdx.x * blockDim.x + threadIdx.x;
  float4 v = reinterpret_cast<const float4*>(src)[i];
  ushort4 o;
  o.x = f32_to_bf16(v.x); o.y = f32_to_bf16(v.y);
  o.z = f32_to_bf16(v.z); o.w = f32_to_bf16(v.w);
  reinterpret_cast<ushort4*>(dst)[i] = o;
}
__global__ void cast2_bf16_kernel(const float* __restrict__ s0, unsigned short* __restrict__ d0,
                                  int n0v, const float* __restrict__ s1,
                                  unsigned short* __restrict__ d1) {
  int i = blockIdx.x * blockDim.x + threadIdx.x;
  const float* s; unsigned short* d; int j;
  if (i < n0v) { s = s0; d = d0; j = i; } else { s = s1; d = d1; j = i - n0v; }
  float4 v = reinterpret_cast<const float4*>(s)[j];
  ushort4 o;
  o.x = f32_to_bf16(v.x); o.y = f32_to_bf16(v.y);
  o.z = f32_to_bf16(v.z); o.w = f32_to_bf16(v.w);
  reinterpret_cast<ushort4*>(d)[j] = o;
}

// ---------------- GEMM: C[M,N] = A[M,K] * W[N,K]^T  (m97 structure) ----------------
__global__ __launch_bounds__(256) void gemm_bt_kernel(
    const unsigned short* __restrict__ A, const unsigned short* __restrict__ Bw,
    float* __restrict__ C, int M, int N, int K) {
  __shared__ unsigned short As[128 * 32];
  __shared__ unsigned short Bs[128 * 32];
  const int tid = threadIdx.x;
  const int bn = blockIdx.x, bm = blockIdx.y;
  const int w = tid >> 6, lane = tid & 63;
  const int wr = w >> 1, wc = w & 1;
  const int lr = lane & 15, lg = lane >> 4;
  const int srow = lane >> 2;
  const int scolb = (lane & 3) * 16;
  f32x4 acc[4][4] = {};
  for (int k0 = 0; k0 < K; k0 += 32) {
    __syncthreads();
#pragma unroll
    for (int i = 0; i < 2; ++i) {
      int row = w * 32 + i * 16 + srow;
      gload_lds16((const char*)A + ((size_t)(bm * 128 + row) * K + k0) * 2 + scolb,
                  (char*)As + w * 2048 + i * 1024);
      gload_lds16((const char*)Bw + ((size_t)(bn * 128 + row) * K + k0) * 2 + scolb,
                  (char*)Bs + w * 2048 + i * 1024);
    }
    __syncthreads();
    bf16x8 af[4], bfr[4];
#pragma unroll
    for (int i = 0; i < 4; ++i)
      af[i] = *reinterpret_cast<const bf16x8*>((char*)As + (wr * 64 + i * 16 + lr) * 64 + lg * 16);
#pragma unroll
    for (int j = 0; j < 4; ++j)
      bfr[j] = *reinterpret_cast<const bf16x8*>((char*)Bs + (wc * 64 + j * 16 + lr) * 64 + lg * 16);
#pragma unroll
    for (int i = 0; i < 4; ++i)
#pragma unroll
      for (int j = 0; j < 4; ++j)
        acc[i][j] = __builtin_amdgcn_mfma_f32_16x16x32_bf16(af[i], bfr[j], acc[i][j], 0, 0, 0);
  }
#pragma unroll
  for (int i = 0; i < 4; ++i) {
    const int m = bm * 128 + wr * 64 + i * 16 + lg * 4;
#pragma unroll
    for (int j = 0; j < 4; ++j) {
      const int n = bn * 128 + wc * 64 + j * 16 + lr;
#pragma unroll
      for (int r = 0; r < 4; ++r)
        C[(size_t)(m + r) * N + n] = acc[i][j][r];
    }
  }
}

// ---------------- RoPE on K + keys output (reads fused XQKV, ld=3072) ----------------
__global__ void rope_k_kernel(const float* __restrict__ xqkv, const float* __restrict__ fc,
                              const float* __restrict__ fs, unsigned short* __restrict__ kbf,
                              float* __restrict__ keys) {
  int idx = blockIdx.x * 256 + threadIdx.x;   // pair index over (b,l,kv,i)
  int i = idx & 63;
  int kvh = (idx >> 6) & 3;
  int l = (idx >> 8) & 2047;
  int b = idx >> 19;
  float2 t = reinterpret_cast<const float2*>(xqkv)[(size_t)(b * 2048 + l) * 1536 + 1024 + kvh * 64 + i];
  float c = fc[l * 64 + i], s = fs[l * 64 + i];
  float r0 = t.x * c - t.y * s;
  float r1 = t.x * s + t.y * c;
  int kidx = ((b * 4 + kvh) * 2048 + l) * 64 + i;
  ushort2 o; o.x = f32_to_bf16(r0); o.y = f32_to_bf16(r1);
  reinterpret_cast<ushort2*>(kbf)[kidx] = o;
  float2 f; f.x = r0; f.y = r1;
#pragma unroll
  for (int rep = 0; rep < 4; ++rep) {
    int h = kvh * 4 + rep;
    reinterpret_cast<float2*>(keys)[((b * 16 + h) * 2048 + l) * 64 + i] = f;
  }
}

// ---------------- V pass: values output + transposed bf16 V ----------------
__global__ void v_proc_kernel(const float* __restrict__ xqkv, unsigned short* __restrict__ vt,
                              float* __restrict__ values) {
  int idx = blockIdx.x * 256 + threadIdx.x;   // element over (b,l,kv,d)
  int d = idx & 127;
  int kvh = (idx >> 7) & 3;
  int l = (idx >> 9) & 2047;
  int b = idx >> 20;
  float v = xqkv[(size_t)(b * 2048 + l) * 3072 + 2560 + kvh * 128 + d];
#pragma unroll
  for (int rep = 0; rep < 4; ++rep) {
    int h = kvh * 4 + rep;
    values[((size_t)(b * 16 + h) * 2048 + l) * 128 + d] = v;
  }
  vt[((size_t)(b * 4 + kvh) * 128 + d) * 2048 + l] = f32_to_bf16(v);
}

// ---------------- causal flash attention v4: double-buffered K/V prefetch ----------------
__global__ __launch_bounds__(256) void attn_kernel(
    const float* __restrict__ xq, const float* __restrict__ fc,
    const float* __restrict__ fs, const unsigned short* __restrict__ kbf,
    const unsigned short* __restrict__ vt, unsigned short* __restrict__ obf) {
  __shared__ unsigned short Ks[2][64 * 128];   // [buf][slot][d], XOR-swizzled, row-permuted
  __shared__ unsigned short Vs[2][128 * 64];   // [buf][d][k], XOR-swizzled
  const int tid = threadIdx.x;
  const int w = tid >> 6, lane = tid & 63;
  const int lr = lane & 15, lg = lane >> 4;
  const int bid = blockIdx.x;
  const int g = bid & 7;                       // XCD slot: one (b,kv) pair per XCD
  const int slot = bid >> 3;
  const int qt = 15 - (slot >> 2);             // strict descending work
  const int rep = slot & 3;
  const int b = g >> 2, kv = g & 3;
  const int h = kv * 4 + rep;
  const float SCALE = 0.08838834764831845f;    // 1/sqrt(128)
  const int swz = (lr & 7) << 4;

  const int qr0 = qt * 128 + w * 16 + lr;
  const int qr1 = qr0 + 64;

  // ---- fused RoPE Q-fragment build (B-operand layout) ----
  bf16x8 qf[2][4];
#pragma unroll
  for (int t = 0; t < 2; ++t) {
    const int qrow = t ? qr1 : qr0;
    const float* xqp = xq + (size_t)(b * 2048 + qrow) * 3072 + h * 128;
    const float* fcp = fc + qrow * 64;
    const float* fsp = fs + qrow * 64;
#pragma unroll
    for (int s = 0; s < 4; ++s) {
      float4 f0 = *reinterpret_cast<const float4*>(xqp + s * 32 + lg * 8);
      float4 f1 = *reinterpret_cast<const float4*>(xqp + s * 32 + lg * 8 + 4);
      float4 c4 = *reinterpret_cast<const float4*>(fcp + s * 16 + lg * 4);
      float4 s4 = *reinterpret_cast<const float4*>(fsp + s * 16 + lg * 4);
      union { bf16x8 v8; unsigned u[4]; } u;
      u.u[0] = pack2(f0.x * c4.x - f0.y * s4.x, f0.x * s4.x + f0.y * c4.x);
      u.u[1] = pack2(f0.z * c4.y - f0.w * s4.y, f0.z * s4.y + f0.w * c4.y);
      u.u[2] = pack2(f1.x * c4.z - f1.y * s4.z, f1.x * s4.z + f1.y * c4.z);
      u.u[3] = pack2(f1.z * c4.w - f1.w * s4.w, f1.z * s4.w + f1.w * c4.w);
      qf[t][s] = u.v8;
    }
  }

  f32x4 acc[2][8] = {};
  float mrow[2] = {-1e30f, -1e30f}, lsum[2] = {0.f, 0.f};

  const char* kgbase = (const char*)(kbf + (size_t)(b * 4 + kv) * 2048 * 128);
  const char* vgbase = (const char*)(vt + (size_t)(b * 4 + kv) * 128 * 2048);

  // staging source offsets (loop-invariant); K global row permuted by pi
  int ksrc[4], vsrc[4];
#pragma unroll
  for (int i = 0; i < 4; ++i) {
    int p = w * 4096 + i * 1024 + lane * 16;
    int krow = p >> 8;
    int kperm = ((krow >> 5) << 5) + ((krow >> 4) & 1) + (((krow >> 2) & 3) << 3) + ((krow & 3) << 1);
    int kcol = (p & 255) ^ ((krow & 7) << 4);
    ksrc[i] = kperm * 256 + kcol;
    int drow = p >> 7;
    int dcol = (p & 127) ^ ((drow & 7) << 4);
    vsrc[i] = drow * 4096 + dcol;
  }

  auto stage = [&](int j, int buf) {
    const int kb = j * 64;
    const char* kg = kgbase + (size_t)kb * 256;
    const char* vg = vgbase + (size_t)kb * 2;
#pragma unroll
    for (int i = 0; i < 4; ++i) {
      gload_lds16(kg + ksrc[i], (char*)Ks[buf] + w * 4096 + i * 1024);
      gload_lds16(vg + vsrc[i], (char*)Vs[buf] + w * 4096 + i * 1024);
    }
  };

  // per-t softmax + in-lane P repack
  auto softmax_t = [&](const f32x4* st, int t, bool mask, int qrow, int kb, bf16x8* pt) {
    float xv[4][4];
    float mt = -1e30f;
#pragma unroll
    for (int c = 0; c < 4; ++c)
#pragma unroll
      for (int r = 0; r < 4; ++r) {
        float v = st[c][r] * SCALE;
        if (mask) {
          int ka = kb + ((c >> 1) << 5) + (c & 1) + 8 * lg + 2 * r;
          v = (ka <= qrow) ? v : -1e30f;
        }
        xv[c][r] = v;
        mt = fmaxf(mt, v);
      }
    mt = fmaxf(mt, __shfl_xor(mt, 16));
    mt = fmaxf(mt, __shfl_xor(mt, 32));
    float facm = 1.0f;
    if (!__all(mt <= mrow[t] + 8.0f)) {        // defer-max (T13)
      float mnew = fmaxf(mrow[t], mt);
      facm = __expf(mrow[t] - mnew);
      mrow[t] = mnew;
#pragma unroll
      for (int dt = 0; dt < 8; ++dt)
#pragma unroll
        for (int r = 0; r < 4; ++r) acc[t][dt][r] *= facm;
    }
    float rs = 0.f;
    float pv[4][4];
#pragma unroll
    for (int c = 0; c < 4; ++c)
#pragma unroll
      for (int r = 0; r < 4; ++r) {
        float p = __expf(xv[c][r] - mrow[t]);
        pv[c][r] = p;
        rs += p;
      }
    rs += __shfl_xor(rs, 16);
    rs += __shfl_xor(rs, 32);
    lsum[t] = lsum[t] * facm + rs;
#pragma unroll
    for (int kk = 0; kk < 2; ++kk) {
      union { bf16x8 v8; unsigned u[4]; } u;
#pragma unroll
      for (int wd = 0; wd < 4; ++wd)
        u.u[wd] = pack2(pv[2 * kk][wd], pv[2 * kk + 1][wd]);
      pt[kk] = u.v8;
    }
  };

  const int nst = 2 * qt + 2;
  stage(0, 0);
  int cur = 0;
  for (int j = 0; j < nst; ++j) {
    __syncthreads();                 // drains prefetch of buf[cur] (issued a full step ago)
    if (j + 1 < nst) stage(j + 1, cur ^ 1);
    const int kb = j * 64;
    const bool only1 = (j == nst - 1);
    const bool do0 = !only1;
    const bool m0 = (j == nst - 2);
    const bool m1 = only1;
    // QK^T (swapped): S^T rows = permuted keys, cols = q
    f32x4 sT0[4], sT1[4];
    __builtin_amdgcn_s_setprio(1);
#pragma unroll
    for (int c = 0; c < 4; ++c) {
      bf16x8 kf[4];
#pragma unroll
      for (int s = 0; s < 4; ++s)
        kf[s] = *reinterpret_cast<const bf16x8*>((char*)Ks[cur] + (((c * 16 + lr) * 256 + s * 64 + lg * 16) ^ swz));
      f32x4 t0 = {0.f, 0.f, 0.f, 0.f}, t1 = {0.f, 0.f, 0.f, 0.f};
#pragma unroll
      for (int s = 0; s < 4; ++s) {
        if (do0) t0 = __builtin_amdgcn_mfma_f32_16x16x32_bf16(kf[s], qf[0][s], t0, 0, 0, 0);
        t1 = __builtin_amdgcn_mfma_f32_16x16x32_bf16(kf[s], qf[1][s], t1, 0, 0, 0);
      }
      sT0[c] = t0; sT1[c] = t1;
    }
    __builtin_amdgcn_s_setprio(0);
    bf16x8 pt0[2], pt1[2];
    if (do0) softmax_t(sT0, 0, m0, qr0, kb, pt0);
    softmax_t(sT1, 1, m1, qr1, kb, pt1);
    // PV: O^T += V^T * P^T
    __builtin_amdgcn_s_setprio(1);
#pragma unroll
    for (int dt = 0; dt < 8; ++dt) {
      bf16x8 v0 = *reinterpret_cast<const bf16x8*>((char*)Vs[cur] + (((dt * 16 + lr) * 128 + lg * 16) ^ swz));
      bf16x8 v1 = *reinterpret_cast<const bf16x8*>((char*)Vs[cur] + (((dt * 16 + lr) * 128 + 64 + lg * 16) ^ swz));
      if (do0) {
        acc[0][dt] = __builtin_amdgcn_mfma_f32_16x16x32_bf16(v0, pt0[0], acc[0][dt], 0, 0, 0);
        acc[0][dt] = __builtin_amdgcn_mfma_f32_16x16x32_bf16(v1, pt0[1], acc[0][dt], 0, 0, 0);
      }
      acc[1][dt] = __builtin_amdgcn_mfma_f32_16x16x32_bf16(v0, pt1[0], acc[1][dt], 0, 0, 0);
      acc[1][dt] = __builtin_amdgcn_mfma_f32_16x16x32_bf16(v1, pt1[1], acc[1][dt], 0, 0, 0);
    }
    __builtin_amdgcn_s_setprio(0);
    cur ^= 1;
  }

#pragma unroll
  for (int t = 0; t < 2; ++t) {
    const int qrow = t ? qr1 : qr0;
    float inv = 1.0f / lsum[t];
#pragma unroll
    for (int dt = 0; dt < 8; ++dt) {
      ushort4 o;
      o.x = f32_to_bf16(acc[t][dt][0] * inv);
      o.y = f32_to_bf16(acc[t][dt][1] * inv);
      o.z = f32_to_bf16(acc[t][dt][2] * inv);
      o.w = f32_to_bf16(acc[t][dt][3] * inv);
      *reinterpret_cast<ushort4*>(obf + ((size_t)(b * 2048 + qrow)) * 2048 + h * 128 + dt * 16 + lg * 4) = o;
    }
  }
}

// ---------------- host launch ----------------
extern "C" void kernel_launch(void* const* d_in, const int* in_sizes, int n_in,
                              void* d_out, int out_size, void* d_ws, size_t ws_size,
                              hipStream_t stream) {
  const float* x  = (const float*)d_in[0];
  const float* fc = (const float*)d_in[1];
  const float* fs = (const float*)d_in[2];
  const float* wq = (const float*)d_in[3];
  const float* wk = (const float*)d_in[4];
  const float* wv = (const float*)d_in[5];
  const float* wo = (const float*)d_in[6];

  float* out    = (float*)d_out;
  float* keys   = out + 8388608;
  float* values = out + 16777216;

  char* ws = (char*)d_ws;
  unsigned short* WQKV = (unsigned short*)(ws + 0);          // 12.6 MB: [wq;wk;wv] (3072 x 2048)
  unsigned short* WO   = (unsigned short*)(ws + 12582912);   // 8 MB
  unsigned short* XBF  = (unsigned short*)(ws + 20971520);   // 16 MB (reused as ATT)
  float*          XQKV = (float*)(ws + 37748736);            // 50.3 MB (4096 x 3072)
  unsigned short* KBF  = (unsigned short*)(ws + 88080384);   // 4 MB
  unsigned short* VTB  = (unsigned short*)(ws + 92274688);   // 4 MB
  unsigned short* ATT  = XBF;                                // alias: XBF dead after projection

  cast2_bf16_kernel<<<8192, 256, 0, stream>>>(wq, WQKV, 1048576, wo, WO);
  cast2_bf16_kernel<<<2048, 256, 0, stream>>>(wk, WQKV + 2048 * 2048, 262144,
                                              wv, WQKV + 2560 * 2048);
  cast_bf16_kernel<<<8192, 256, 0, stream>>>(x, XBF);

  // fused QKV projection: C (4096 x 3072) = XBF (4096 x 2048) * WQKV^T
  gemm_bt_kernel<<<dim3(24, 32), 256, 0, stream>>>(XBF, WQKV, XQKV, 4096, 3072, 2048);

  rope_k_kernel<<<4096, 256, 0, stream>>>(XQKV, fc, fs, KBF, keys);
  v_proc_kernel<<<8192, 256, 0, stream>>>(XQKV, VTB, values);

  attn_kernel<<<512, 256, 0, stream>>>(XQKV, fc, fs, KBF, VTB, ATT);

  gemm_bt_kernel<<<dim3(16, 32), 256, 0, stream>>>(ATT, WO, out, 4096, 2048, 2048);
}